// Round 7
// baseline (127.952 us; speedup 1.0000x reference)
//
#include <hip/hip_runtime.h>
#include <hip/hip_bf16.h>

#define B_  8
#define S_  2048
#define D_  1024
#define E_  16
#define SD_ 64
#define SH_ 256
#define H_  4096
#define R_  (D_ * S_)      // 2097152 rows of w_switch (MAX_SEQ == S)
#define NBLK_ 8192         // router blocks (burst-style: 256 rows/block)

typedef __attribute__((ext_vector_type(8))) short bf16x8;
typedef __attribute__((ext_vector_type(4))) float f32x4;

static __device__ __forceinline__ short f2bf(float f) {
    union { float f; unsigned u; } v; v.f = f;
    unsigned r = v.u + 0x7fffu + ((v.u >> 16) & 1u);   // RNE to bf16
    return (short)(r >> 16);
}

// ---------------------------------------------------------------------------
// Convert w1 [16][64][256] + w2 [4096][1024] fp32 -> MFMA B-fragment bf16.
// Blocks [0,128): w1; blocks [128,2176): w2.
// ---------------------------------------------------------------------------
__global__ void convert_w(const float* __restrict__ w1, const float* __restrict__ w2,
                          short* __restrict__ w1f, short* __restrict__ w2f) {
    int blk = blockIdx.x;
    if (blk < 128) {
        int t = blk * 256 + threadIdx.x;              // 32768 threads
        int lane = t & 63, ntile = (t >> 6) & 15, ks = (t >> 10) & 1, e = t >> 11;
        int k0 = ks * 32 + ((lane >> 4) << 3);
        int n  = (ntile << 4) + (lane & 15);
        const float* src = w1 + ((size_t)(e * 64 + k0) * 256 + n);
        bf16x8 o;
        #pragma unroll
        for (int j = 0; j < 8; ++j) o[j] = f2bf(src[(size_t)j * 256]);
        *(bf16x8*)(w1f + ((size_t)t << 3)) = o;
    } else {
        int t = (blk - 128) * 256 + threadIdx.x;      // 524288 threads
        int lane = t & 63, ntile = (t >> 6) & 63, kg = t >> 12;   // kg < 128
        int k0 = (kg << 5) + ((lane >> 4) << 3);
        int n  = (ntile << 4) + (lane & 15);
        const float* src = w2 + ((size_t)k0 * 1024 + n);
        bf16x8 o;
        #pragma unroll
        for (int j = 0; j < 8; ++j) o[j] = f2bf(src[(size_t)j * 1024]);
        *(bf16x8*)(w2f + ((size_t)t << 3)) = o;
    }
}

// ---------------------------------------------------------------------------
// Router, burst-style (convert_w-shaped): logits[b][e] = sum_i x[b][i]*w[i][e]
// Wave owns 64 rows, NO loop over memory: all 36 loads (4 w-float4 +
// 32 x-scalars) issue as one independent burst from fixed bases with
// imm offsets, then 128 FMAs, shuffle-reduce, one partial write, retire.
// Memory parallelism comes from wave churn (32768 short-lived waves),
// which is the pattern convert_w/mlp prove runs at >5 TB/s here.
//   lane: q = lane&3 (expert quad), rsub = lane>>2 (row-in-16).
//   w: wp[it*64] = 1 KB contiguous per instr (16 rows x 4 quads).
//   x: per (it,b) 64 B contiguous across lanes (8 segments/instr).
// partials layout: [entry(128)][block(8192)]
// ---------------------------------------------------------------------------
__global__ __launch_bounds__(256, 4) void router_kernel(const float* __restrict__ x,
                                                        const float* __restrict__ wsw,
                                                        float* __restrict__ partials) {
    __shared__ float red[512];
    int tid = threadIdx.x;
    int wid = tid >> 6, lane = tid & 63;
    int q = lane & 3, rsub = lane >> 2;                // row within 16
    size_t wavebase = (((size_t)blockIdx.x << 2) + wid) << 6;   // 64 rows/wave
    const float4* wp = (const float4*)wsw + (wavebase << 2) + lane;

    // ---- burst loads: all independent ----
    float4 w0 = wp[0];
    float4 w1 = wp[64];
    float4 w2 = wp[128];
    float4 w3 = wp[192];
    float xv[4][8];
    #pragma unroll
    for (int b = 0; b < 8; ++b) {
        const float* xb = x + (size_t)b * R_ + wavebase + rsub;
        #pragma unroll
        for (int it = 0; it < 4; ++it)
            xv[it][b] = xb[it << 4];
    }

    // ---- compute ----
    float acc[8][4];
    #pragma unroll
    for (int b = 0; b < 8; ++b)
        #pragma unroll
        for (int j = 0; j < 4; ++j) acc[b][j] = 0.f;

    #define FMA4(W, IT)                                             \
        _Pragma("unroll")                                           \
        for (int b = 0; b < 8; ++b) {                               \
            float xs = xv[IT][b];                                   \
            acc[b][0] = fmaf(xs, (W).x, acc[b][0]);                 \
            acc[b][1] = fmaf(xs, (W).y, acc[b][1]);                 \
            acc[b][2] = fmaf(xs, (W).z, acc[b][2]);                 \
            acc[b][3] = fmaf(xs, (W).w, acc[b][3]);                 \
        }
    FMA4(w0, 0)
    FMA4(w1, 1)
    FMA4(w2, 2)
    FMA4(w3, 3)
    #undef FMA4

    // reduce across the 16 lanes sharing q (xor 4,8,16,32)
    #pragma unroll
    for (int b = 0; b < 8; ++b)
        #pragma unroll
        for (int j = 0; j < 4; ++j) {
            float v = acc[b][j];
            v += __shfl_xor(v, 4);
            v += __shfl_xor(v, 8);
            v += __shfl_xor(v, 16);
            v += __shfl_xor(v, 32);
            acc[b][j] = v;
        }

    if (lane < 4) {
        #pragma unroll
        for (int b = 0; b < 8; ++b)
            #pragma unroll
            for (int j = 0; j < 4; ++j)
                red[(wid << 7) + b * 16 + q * 4 + j] = acc[b][j];
    }
    __syncthreads();
    if (tid < 128)
        partials[(size_t)tid * NBLK_ + blockIdx.x] =
            red[tid] + red[128 + tid] + red[256 + tid] + red[384 + tid];
}

// ---------------------------------------------------------------------------
// Reduce partials[128][8192] -> logits[128]
// ---------------------------------------------------------------------------
__global__ __launch_bounds__(256) void reduce_kernel(const float* __restrict__ partials,
                                                     float* __restrict__ logits) {
    __shared__ float s[256];
    int e = blockIdx.x, tid = threadIdx.x;
    const float4* p4 = (const float4*)(partials + (size_t)e * NBLK_);
    float t = 0.f;
    #pragma unroll
    for (int i = 0; i < 8; ++i) {
        float4 v = p4[i * 256 + tid];
        t += v.x + v.y + v.z + v.w;
    }
    s[tid] = t;
    __syncthreads();
    #pragma unroll
    for (int off = 128; off; off >>= 1) {
        if (tid < off) s[tid] += s[tid + off];
        __syncthreads();
    }
    if (tid == 0) logits[e] = s[0];
}

// ---------------------------------------------------------------------------
// Top-2 per batch (softmax is monotone). Ties -> lower index.
// ---------------------------------------------------------------------------
__global__ void topk_kernel(const float* __restrict__ logits,
                            const float* __restrict__ bsw,
                            int* __restrict__ experts) {
    int b = threadIdx.x;
    if (b >= 8) return;
    float v[16];
    #pragma unroll
    for (int e = 0; e < 16; ++e) v[e] = logits[b * 16 + e] + bsw[e];
    int i0 = 0; float m0 = v[0];
    #pragma unroll
    for (int e = 1; e < 16; ++e) if (v[e] > m0) { m0 = v[e]; i0 = e; }
    int i1 = -1; float m1 = -3.4e38f;
    #pragma unroll
    for (int e = 0; e < 16; ++e) if (e != i0 && v[e] > m1) { m1 = v[e]; i1 = e; }
    experts[2 * b]     = i0;
    experts[2 * b + 1] = i1;
}

// ---------------------------------------------------------------------------
// Fused expert MLP (unchanged — passed with absmax 0.0078)
// ---------------------------------------------------------------------------
__global__ __launch_bounds__(256, 2) void mlp_kernel(
        const float* __restrict__ x, const int* __restrict__ experts,
        const short* __restrict__ w1f, const float* __restrict__ b1,
        const short* __restrict__ w2f, const float* __restrict__ b2,
        float* __restrict__ out) {
    __shared__ short G[32][520];

    int blk  = blockIdx.x;
    int b    = blk & 7;            // XCD-friendly: batch = blk%8
    int tok0 = (blk >> 3) << 5;
    int e0 = experts[2 * b], e1 = experts[2 * b + 1];
    int tid = threadIdx.x;
    int wid = tid >> 6, lane = tid & 63;
    int slot  = wid >> 1;
    int ex    = slot ? e1 : e0;
    int nhalf = wid & 1;
    int lrow = lane & 15, lk8 = (lane >> 4) << 3;

    f32x4 acc1[2][8];
    #pragma unroll
    for (int m = 0; m < 2; ++m)
        #pragma unroll
        for (int n = 0; n < 8; ++n) acc1[m][n] = (f32x4){0.f, 0.f, 0.f, 0.f};

    #pragma unroll
    for (int ks = 0; ks < 2; ++ks) {
        bf16x8 a[2];
        #pragma unroll
        for (int m = 0; m < 2; ++m) {
            const float* xp = x + (((size_t)b * S_ + tok0 + m * 16 + lrow) * D_
                                   + ex * 64 + ks * 32 + lk8);
            float4 f0 = *(const float4*)xp;
            float4 f1 = *(const float4*)(xp + 4);
            bf16x8 av;
            av[0] = f2bf(f0.x); av[1] = f2bf(f0.y); av[2] = f2bf(f0.z); av[3] = f2bf(f0.w);
            av[4] = f2bf(f1.x); av[5] = f2bf(f1.y); av[6] = f2bf(f1.z); av[7] = f2bf(f1.w);
            a[m] = av;
        }
        #pragma unroll
        for (int nt = 0; nt < 8; ++nt) {
            int ntg = nhalf * 8 + nt;
            bf16x8 bf = *(const bf16x8*)(w1f + ((((size_t)(ex * 2 + ks) * 16 + ntg) * 64 + lane) << 3));
            acc1[0][nt] = __builtin_amdgcn_mfma_f32_16x16x32_bf16(a[0], bf, acc1[0][nt], 0, 0, 0);
            acc1[1][nt] = __builtin_amdgcn_mfma_f32_16x16x32_bf16(a[1], bf, acc1[1][nt], 0, 0, 0);
        }
    }

    #pragma unroll
    for (int nt = 0; nt < 8; ++nt) {
        int ncol = (nhalf * 8 + nt) * 16 + lrow;
        float bb = b1[ex * 256 + ncol];
        #pragma unroll
        for (int m = 0; m < 2; ++m) {
            int r0 = m * 16 + ((lane >> 4) << 2);
            #pragma unroll
            for (int r = 0; r < 4; ++r) {
                float v = acc1[m][nt][r] + bb;
                v = 0.5f * v * (1.0f + erff(v * 0.70710678118f));
                G[r0 + r][slot * 256 + ncol] = f2bf(v);
            }
        }
    }
    __syncthreads();

    f32x4 acc2[2][16];
    #pragma unroll
    for (int m = 0; m < 2; ++m)
        #pragma unroll
        for (int n = 0; n < 16; ++n) acc2[m][n] = (f32x4){0.f, 0.f, 0.f, 0.f};

    for (int ks = 0; ks < 16; ++ks) {
        int e  = (ks < 8) ? e0 : e1;
        int kg = e * 8 + (ks & 7);
        bf16x8 a0 = *(const bf16x8*)&G[lrow][ks * 32 + lk8];
        bf16x8 a1 = *(const bf16x8*)&G[16 + lrow][ks * 32 + lk8];
        #pragma unroll
        for (int nt = 0; nt < 16; ++nt) {
            int ntg = wid * 16 + nt;
            bf16x8 bf = *(const bf16x8*)(w2f + ((((size_t)kg * 64 + ntg) * 64 + lane) << 3));
            acc2[0][nt] = __builtin_amdgcn_mfma_f32_16x16x32_bf16(a0, bf, acc2[0][nt], 0, 0, 0);
            acc2[1][nt] = __builtin_amdgcn_mfma_f32_16x16x32_bf16(a1, bf, acc2[1][nt], 0, 0, 0);
        }
    }

    size_t obase = ((size_t)b * S_ + tok0) * D_;
    #pragma unroll
    for (int nt = 0; nt < 16; ++nt) {
        int d = wid * 256 + nt * 16 + lrow;
        float bb = b2[d];
        #pragma unroll
        for (int m = 0; m < 2; ++m) {
            int r0 = m * 16 + ((lane >> 4) << 2);
            #pragma unroll
            for (int r = 0; r < 4; ++r)
                out[obase + (size_t)(r0 + r) * D_ + d] = acc2[m][nt][r] + bb;
        }
    }
}

// ---------------------------------------------------------------------------
extern "C" void kernel_launch(void* const* d_in, const int* in_sizes, int n_in,
                              void* d_out, int out_size, void* d_ws, size_t ws_size,
                              hipStream_t stream) {
    const float* x   = (const float*)d_in[0];
    const float* wsw = (const float*)d_in[1];
    const float* bsw = (const float*)d_in[2];
    const float* w1  = (const float*)d_in[3];
    const float* b1  = (const float*)d_in[4];
    const float* w2  = (const float*)d_in[5];
    const float* b2  = (const float*)d_in[6];
    float* out = (float*)d_out;

    int*   experts  = (int*)d_ws;                                    // 64 B
    float* logits   = (float*)((char*)d_ws + 512);                   // 512 B
    float* partials = (float*)((char*)d_ws + 4096);                  // 128*8192*4 = 4 MB
    short* w1f = (short*)((char*)d_ws + 4096 + 4194304);             // 512 KB
    short* w2f = (short*)((char*)d_ws + 4096 + 4194304 + 524288);    // 8 MB

    router_kernel<<<NBLK_, 256, 0, stream>>>(x, wsw, partials);
    reduce_kernel<<<128, 256, 0, stream>>>(partials, logits);
    topk_kernel<<<1, 64, 0, stream>>>(logits, bsw, experts);
    convert_w<<<2176, 256, 0, stream>>>(w1, w2, w1f, w2f);
    mlp_kernel<<<512, 256, 0, stream>>>(x, experts, w1f, b1, w2f, b2, out);
}

// Round 8
// 110.386 us; speedup vs baseline: 1.1591x; 1.1591x over previous
//
#include <hip/hip_runtime.h>
#include <hip/hip_bf16.h>

#define B_  8
#define S_  2048
#define D_  1024
#define E_  16
#define SD_ 64
#define SH_ 256
#define H_  4096
#define R_  (D_ * S_)        // 2097152 rows of w_switch (MAX_SEQ == S)
#define NBLK_ 1024           // router blocks
#define RT_ROWS 2048         // rows per router block
#define RT_CHUNK 128         // rows per staged chunk
#define RT_NCHUNK 16

typedef __attribute__((ext_vector_type(8))) short bf16x8;
typedef __attribute__((ext_vector_type(4))) float f32x4;

static __device__ __forceinline__ short f2bf(float f) {
    union { float f; unsigned u; } v; v.f = f;
    unsigned r = v.u + 0x7fffu + ((v.u >> 16) & 1u);   // RNE to bf16
    return (short)(r >> 16);
}

// async global->LDS, 16 B per lane: dst (wave-uniform) + lane*16, src per-lane
static __device__ __forceinline__ void gload16(const float* g, float* l) {
    __builtin_amdgcn_global_load_lds(
        (const __attribute__((address_space(1))) void*)g,
        (__attribute__((address_space(3))) void*)l,
        16, 0, 0);
}

// ---------------------------------------------------------------------------
// Convert w1 [16][64][256] + w2 [4096][1024] fp32 -> MFMA B-fragment bf16.
// ---------------------------------------------------------------------------
__global__ void convert_w(const float* __restrict__ w1, const float* __restrict__ w2,
                          short* __restrict__ w1f, short* __restrict__ w2f) {
    int blk = blockIdx.x;
    if (blk < 128) {
        int t = blk * 256 + threadIdx.x;              // 32768 threads
        int lane = t & 63, ntile = (t >> 6) & 15, ks = (t >> 10) & 1, e = t >> 11;
        int k0 = ks * 32 + ((lane >> 4) << 3);
        int n  = (ntile << 4) + (lane & 15);
        const float* src = w1 + ((size_t)(e * 64 + k0) * 256 + n);
        bf16x8 o;
        #pragma unroll
        for (int j = 0; j < 8; ++j) o[j] = f2bf(src[(size_t)j * 256]);
        *(bf16x8*)(w1f + ((size_t)t << 3)) = o;
    } else {
        int t = (blk - 128) * 256 + threadIdx.x;      // 524288 threads
        int lane = t & 63, ntile = (t >> 6) & 63, kg = t >> 12;   // kg < 128
        int k0 = (kg << 5) + ((lane >> 4) << 3);
        int n  = (ntile << 4) + (lane & 15);
        const float* src = w2 + ((size_t)k0 * 1024 + n);
        bf16x8 o;
        #pragma unroll
        for (int j = 0; j < 8; ++j) o[j] = f2bf(src[(size_t)j * 1024]);
        *(bf16x8*)(w2f + ((size_t)t << 3)) = o;
    }
}

// ---------------------------------------------------------------------------
// Router, m97-shaped: ALL global traffic via fat linear global_load_lds
// staging; compute reads from LDS only; double-buffered chunks, one barrier
// per chunk. Block owns 2048 rows = 16 chunks x 128 rows.
// Per chunk (12 KB): w rows [128][16]f32 (8 KB, 8 gload slots) +
// x segs [8 batches][128 rows] (4 KB, 4 gload slots; per-lane src splits b).
// Inner: lane (q=lane&3, rh=lane>>2); wave w computes rows w*32+{0,16}+rh:
//   w via ds_read_b128 (lw[r][4q..]), x via 4-way-broadcast ds_read_b32.
// acc[8][4] fp32 (exact). Tail reduce identical to verified rounds.
// partials layout: [entry(128)][block(1024)]
// ---------------------------------------------------------------------------
__global__ __launch_bounds__(256, 4) void router_kernel(const float* __restrict__ x,
                                                        const float* __restrict__ wsw,
                                                        float* __restrict__ partials) {
    __shared__ float lw[2][RT_CHUNK * 16];   // 2 x 8 KB
    __shared__ float lx[2][8 * RT_CHUNK];    // 2 x 4 KB
    __shared__ float red[512];

    int tid = threadIdx.x;
    int wid = tid >> 6, lane = tid & 63;
    int q = lane & 3, rh = lane >> 2;
    size_t base = (size_t)blockIdx.x * RT_ROWS;

    // stage chunk -> buf: 12 slots, 3 per wave, all wave-uniform dests
    #define STAGE(BUF, CHUNK)                                                   \
        {   size_t cb = base + (size_t)(CHUNK) * RT_CHUNK;                      \
            _Pragma("unroll")                                                   \
            for (int k = 0; k < 3; ++k) {                                       \
                int s = wid * 3 + k;                                            \
                if (s < 8) {                                                    \
                    gload16(wsw + (cb + s * 16) * 16 + lane * 4,                \
                            &lw[BUF][s * 256]);                                 \
                } else {                                                        \
                    int s2 = s - 8;                                             \
                    int b = 2 * s2 + (lane >> 5);                               \
                    gload16(x + (size_t)b * R_ + cb + (size_t)(lane & 31) * 4,  \
                            &lx[BUF][s2 * 256]);                                \
                }                                                               \
            }                                                                   \
        }

    float acc[8][4];
    #pragma unroll
    for (int b = 0; b < 8; ++b)
        #pragma unroll
        for (int j = 0; j < 4; ++j) acc[b][j] = 0.f;

    STAGE(0, 0)
    __syncthreads();

    for (int c = 0; c < RT_NCHUNK; ++c) {
        int cur = c & 1;
        if (c + 1 < RT_NCHUNK) STAGE(cur ^ 1, c + 1)

        #pragma unroll
        for (int half = 0; half < 2; ++half) {
            int r = (wid << 5) + (half << 4) + rh;          // row within chunk
            float4 w = *(const float4*)&lw[cur][r * 16 + q * 4];
            #pragma unroll
            for (int b = 0; b < 8; ++b) {
                float xv = lx[cur][b * RT_CHUNK + r];
                acc[b][0] = fmaf(xv, w.x, acc[b][0]);
                acc[b][1] = fmaf(xv, w.y, acc[b][1]);
                acc[b][2] = fmaf(xv, w.z, acc[b][2]);
                acc[b][3] = fmaf(xv, w.w, acc[b][3]);
            }
        }
        __syncthreads();   // publishes next chunk (vmcnt drained), frees cur
    }
    #undef STAGE

    // reduce across the 16 lanes sharing q (xor 4,8,16,32) — verified tail
    #pragma unroll
    for (int b = 0; b < 8; ++b)
        #pragma unroll
        for (int j = 0; j < 4; ++j) {
            float v = acc[b][j];
            v += __shfl_xor(v, 4);
            v += __shfl_xor(v, 8);
            v += __shfl_xor(v, 16);
            v += __shfl_xor(v, 32);
            acc[b][j] = v;
        }

    if (lane < 4) {
        #pragma unroll
        for (int b = 0; b < 8; ++b)
            #pragma unroll
            for (int j = 0; j < 4; ++j)
                red[(wid << 7) + b * 16 + q * 4 + j] = acc[b][j];
    }
    __syncthreads();
    if (tid < 128)
        partials[(size_t)tid * NBLK_ + blockIdx.x] =
            red[tid] + red[128 + tid] + red[256 + tid] + red[384 + tid];
}

// ---------------------------------------------------------------------------
// Reduce partials[128][1024] -> logits[128]
// ---------------------------------------------------------------------------
__global__ __launch_bounds__(256) void reduce_kernel(const float* __restrict__ partials,
                                                     float* __restrict__ logits) {
    __shared__ float s[256];
    int e = blockIdx.x, tid = threadIdx.x;
    const float4* p4 = (const float4*)(partials + (size_t)e * NBLK_);
    float4 v = p4[tid];
    s[tid] = v.x + v.y + v.z + v.w;
    __syncthreads();
    #pragma unroll
    for (int off = 128; off; off >>= 1) {
        if (tid < off) s[tid] += s[tid + off];
        __syncthreads();
    }
    if (tid == 0) logits[e] = s[0];
}

// ---------------------------------------------------------------------------
// Top-2 per batch (softmax is monotone). Ties -> lower index.
// ---------------------------------------------------------------------------
__global__ void topk_kernel(const float* __restrict__ logits,
                            const float* __restrict__ bsw,
                            int* __restrict__ experts) {
    int b = threadIdx.x;
    if (b >= 8) return;
    float v[16];
    #pragma unroll
    for (int e = 0; e < 16; ++e) v[e] = logits[b * 16 + e] + bsw[e];
    int i0 = 0; float m0 = v[0];
    #pragma unroll
    for (int e = 1; e < 16; ++e) if (v[e] > m0) { m0 = v[e]; i0 = e; }
    int i1 = -1; float m1 = -3.4e38f;
    #pragma unroll
    for (int e = 0; e < 16; ++e) if (e != i0 && v[e] > m1) { m1 = v[e]; i1 = e; }
    experts[2 * b]     = i0;
    experts[2 * b + 1] = i1;
}

// ---------------------------------------------------------------------------
// Fused expert MLP (unchanged — passed with absmax 0.0078)
// ---------------------------------------------------------------------------
__global__ __launch_bounds__(256, 2) void mlp_kernel(
        const float* __restrict__ x, const int* __restrict__ experts,
        const short* __restrict__ w1f, const float* __restrict__ b1,
        const short* __restrict__ w2f, const float* __restrict__ b2,
        float* __restrict__ out) {
    __shared__ short G[32][520];

    int blk  = blockIdx.x;
    int b    = blk & 7;            // XCD-friendly: batch = blk%8
    int tok0 = (blk >> 3) << 5;
    int e0 = experts[2 * b], e1 = experts[2 * b + 1];
    int tid = threadIdx.x;
    int wid = tid >> 6, lane = tid & 63;
    int slot  = wid >> 1;
    int ex    = slot ? e1 : e0;
    int nhalf = wid & 1;
    int lrow = lane & 15, lk8 = (lane >> 4) << 3;

    f32x4 acc1[2][8];
    #pragma unroll
    for (int m = 0; m < 2; ++m)
        #pragma unroll
        for (int n = 0; n < 8; ++n) acc1[m][n] = (f32x4){0.f, 0.f, 0.f, 0.f};

    #pragma unroll
    for (int ks = 0; ks < 2; ++ks) {
        bf16x8 a[2];
        #pragma unroll
        for (int m = 0; m < 2; ++m) {
            const float* xp = x + (((size_t)b * S_ + tok0 + m * 16 + lrow) * D_
                                   + ex * 64 + ks * 32 + lk8);
            float4 f0 = *(const float4*)xp;
            float4 f1 = *(const float4*)(xp + 4);
            bf16x8 av;
            av[0] = f2bf(f0.x); av[1] = f2bf(f0.y); av[2] = f2bf(f0.z); av[3] = f2bf(f0.w);
            av[4] = f2bf(f1.x); av[5] = f2bf(f1.y); av[6] = f2bf(f1.z); av[7] = f2bf(f1.w);
            a[m] = av;
        }
        #pragma unroll
        for (int nt = 0; nt < 8; ++nt) {
            int ntg = nhalf * 8 + nt;
            bf16x8 bf = *(const bf16x8*)(w1f + ((((size_t)(ex * 2 + ks) * 16 + ntg) * 64 + lane) << 3));
            acc1[0][nt] = __builtin_amdgcn_mfma_f32_16x16x32_bf16(a[0], bf, acc1[0][nt], 0, 0, 0);
            acc1[1][nt] = __builtin_amdgcn_mfma_f32_16x16x32_bf16(a[1], bf, acc1[1][nt], 0, 0, 0);
        }
    }

    #pragma unroll
    for (int nt = 0; nt < 8; ++nt) {
        int ncol = (nhalf * 8 + nt) * 16 + lrow;
        float bb = b1[ex * 256 + ncol];
        #pragma unroll
        for (int m = 0; m < 2; ++m) {
            int r0 = m * 16 + ((lane >> 4) << 2);
            #pragma unroll
            for (int r = 0; r < 4; ++r) {
                float v = acc1[m][nt][r] + bb;
                v = 0.5f * v * (1.0f + erff(v * 0.70710678118f));
                G[r0 + r][slot * 256 + ncol] = f2bf(v);
            }
        }
    }
    __syncthreads();

    f32x4 acc2[2][16];
    #pragma unroll
    for (int m = 0; m < 2; ++m)
        #pragma unroll
        for (int n = 0; n < 16; ++n) acc2[m][n] = (f32x4){0.f, 0.f, 0.f, 0.f};

    for (int ks = 0; ks < 16; ++ks) {
        int e  = (ks < 8) ? e0 : e1;
        int kg = e * 8 + (ks & 7);
        bf16x8 a0 = *(const bf16x8*)&G[lrow][ks * 32 + lk8];
        bf16x8 a1 = *(const bf16x8*)&G[16 + lrow][ks * 32 + lk8];
        #pragma unroll
        for (int nt = 0; nt < 16; ++nt) {
            int ntg = wid * 16 + nt;
            bf16x8 bf = *(const bf16x8*)(w2f + ((((size_t)kg * 64 + ntg) * 64 + lane) << 3));
            acc2[0][nt] = __builtin_amdgcn_mfma_f32_16x16x32_bf16(a0, bf, acc2[0][nt], 0, 0, 0);
            acc2[1][nt] = __builtin_amdgcn_mfma_f32_16x16x32_bf16(a1, bf, acc2[1][nt], 0, 0, 0);
        }
    }

    size_t obase = ((size_t)b * S_ + tok0) * D_;
    #pragma unroll
    for (int nt = 0; nt < 16; ++nt) {
        int d = wid * 256 + nt * 16 + lrow;
        float bb = b2[d];
        #pragma unroll
        for (int m = 0; m < 2; ++m) {
            int r0 = m * 16 + ((lane >> 4) << 2);
            #pragma unroll
            for (int r = 0; r < 4; ++r)
                out[obase + (size_t)(r0 + r) * D_ + d] = acc2[m][nt][r] + bb;
        }
    }
}

// ---------------------------------------------------------------------------
extern "C" void kernel_launch(void* const* d_in, const int* in_sizes, int n_in,
                              void* d_out, int out_size, void* d_ws, size_t ws_size,
                              hipStream_t stream) {
    const float* x   = (const float*)d_in[0];
    const float* wsw = (const float*)d_in[1];
    const float* bsw = (const float*)d_in[2];
    const float* w1  = (const float*)d_in[3];
    const float* b1  = (const float*)d_in[4];
    const float* w2  = (const float*)d_in[5];
    const float* b2  = (const float*)d_in[6];
    float* out = (float*)d_out;

    int*   experts  = (int*)d_ws;                                    // 64 B
    float* logits   = (float*)((char*)d_ws + 512);                   // 512 B
    float* partials = (float*)((char*)d_ws + 4096);                  // 128*1024*4 = 512 KB
    short* w1f = (short*)((char*)d_ws + 4096 + 524288);              // 512 KB
    short* w2f = (short*)((char*)d_ws + 4096 + 524288 + 524288);     // 8 MB

    router_kernel<<<NBLK_, 256, 0, stream>>>(x, wsw, partials);
    reduce_kernel<<<128, 256, 0, stream>>>(partials, logits);
    topk_kernel<<<1, 64, 0, stream>>>(logits, bsw, experts);
    convert_w<<<2176, 256, 0, stream>>>(w1, w2, w1f, w2f);
    mlp_kernel<<<512, 256, 0, stream>>>(x, experts, w1f, b1, w2f, b2, out);
}